// Round 9
// baseline (272.841 us; speedup 1.0000x reference)
//
#include <hip/hip_runtime.h>
#include <hip/hip_bf16.h>
#include <stdint.h>

// B=4, C=512, H=W=64 -> N=4096. Channel-first x [B,C,N].
#define C_DIM 512
#define N_DIM 4096
#define B_DIM 4

typedef __bf16 bf16x8 __attribute__((ext_vector_type(8)));
typedef float f32x4 __attribute__((ext_vector_type(4)));
#define AS1 __attribute__((address_space(1)))
#define AS3 __attribute__((address_space(3)))

static __device__ __forceinline__ unsigned short f2bf(float x) {
  unsigned u = __float_as_uint(x);
  unsigned r = (u + 0x7fffu + ((u >> 16) & 1u)) >> 16;
  return (unsigned short)r;
}

// convert weights to bf16; transpose wq,wk,wv (z=0,1,2), straight-copy wp (z=3)
__global__ __launch_bounds__(256) void cvtT_weights(
    const float* __restrict__ wq, const float* __restrict__ wk,
    const float* __restrict__ wv, const float* __restrict__ wp,
    unsigned short* __restrict__ oq, unsigned short* __restrict__ ok,
    unsigned short* __restrict__ ov, unsigned short* __restrict__ op) {
  __shared__ float t[32][33];
  const int zz = blockIdx.z;
  const float* w = zz == 0 ? wq : zz == 1 ? wk : zz == 2 ? wv : wp;
  unsigned short* o = zz == 0 ? oq : zz == 1 ? ok : zz == 2 ? ov : op;
  const int r0 = blockIdx.y * 32, c0 = blockIdx.x * 32;
  const int tx = threadIdx.x, ty = threadIdx.y;
  if (zz < 3) {
    #pragma unroll
    for (int i = ty; i < 32; i += 8) t[i][tx] = w[(r0 + i) * C_DIM + c0 + tx];
    __syncthreads();
    #pragma unroll
    for (int i = ty; i < 32; i += 8)
      o[(size_t)(c0 + i) * C_DIM + r0 + tx] = f2bf(t[tx][i]);
  } else {
    #pragma unroll
    for (int i = ty; i < 32; i += 8)
      o[(size_t)(r0 + i) * C_DIM + c0 + tx] = f2bf(w[(r0 + i) * C_DIM + c0 + tx]);
  }
}

// u[c] = sum_o wk[o,c]*bq[o] (blocks 0-7); bvp[o] = sum_m wp[o,m]*bv[m] (8-15)
__global__ __launch_bounds__(64) void vec_prep(
    const float* __restrict__ wk, const float* __restrict__ bq,
    const float* __restrict__ wp, const float* __restrict__ bv,
    float* __restrict__ u, float* __restrict__ bvp) {
  const int b = blockIdx.x;
  const int t = (b & 7) * 64 + threadIdx.x;
  if (b < 8) {
    float s = 0.f;
    #pragma unroll 8
    for (int o = 0; o < C_DIM; ++o) s += wk[(size_t)o * C_DIM + t] * bq[o];
    u[t] = s;
  } else {
    float s = 0.f;
    #pragma unroll 8
    for (int m = 0; m < C_DIM; ++m) s += wp[(size_t)t * C_DIM + m] * bv[m];
    bvp[t] = s;
  }
}

// x [B,C,N] f32 -> Xt [B,N,C] bf16
__global__ __launch_bounds__(256) void transpose_x(
    const float* __restrict__ x, unsigned short* __restrict__ Xt) {
  __shared__ float t[32][33];
  const int b = blockIdx.z;
  const float* xb = x + (size_t)b * C_DIM * N_DIM;
  unsigned short* xtb = Xt + (size_t)b * N_DIM * C_DIM;
  const int n0 = blockIdx.x * 32, c0 = blockIdx.y * 32;
  const int tx = threadIdx.x, ty = threadIdx.y;
  #pragma unroll
  for (int i = ty; i < 32; i += 8)
    t[i][tx] = xb[(size_t)(c0 + i) * N_DIM + n0 + tx];
  __syncthreads();
  #pragma unroll
  for (int i = ty; i < 32; i += 8)
    xtb[(size_t)(n0 + i) * C_DIM + c0 + tx] = f2bf(t[tx][i]);
}

// T[row] = rs * sum_c Xt[row,c]*u[c]   (wave per row, 4 rows/block)
__global__ __launch_bounds__(256) void rowdot_T(
    const unsigned short* __restrict__ Xt, const float* __restrict__ u,
    float* __restrict__ T) {
  const int row = blockIdx.x * 4 + (threadIdx.x >> 6);
  const int lane = threadIdx.x & 63;
  uint4 v = *reinterpret_cast<const uint4*>(Xt + (size_t)row * C_DIM + lane * 8);
  unsigned ua[4] = {v.x, v.y, v.z, v.w};
  const float* up = u + lane * 8;
  float s = 0.f;
  #pragma unroll
  for (int i = 0; i < 4; ++i) {
    s += __uint_as_float(ua[i] << 16) * up[2 * i];
    s += __uint_as_float(ua[i] & 0xffff0000u) * up[2 * i + 1];
  }
  #pragma unroll
  for (int off = 32; off >= 1; off >>= 1) s += __shfl_xor(s, off);
  if (lane == 0) T[row] = 0.044194173824159216f * s;
}

// ---------------- 128^2-tile 2-phase NT GEMM body (small/mid GEMMs) --------
// C[i,j] = sum_k A[i,k]B[j,k]; BIAS: 0 none, 2 +bias[row]. bf16 out.
template<int BIAS>
__device__ __forceinline__ void gemm128_body(
    unsigned short* As, unsigned short* Bs,
    const unsigned short* __restrict__ A, const unsigned short* __restrict__ B,
    unsigned short* __restrict__ C, int K, int ldc,
    const float* __restrict__ bias, int bx, int by) {
  const int tid = threadIdx.x;
  const int wid = tid >> 6, lane = tid & 63;
  const int wm = (wid >> 1) * 64, wn = (wid & 1) * 64;
  f32x4 acc[4][4] = {};
  const size_t rowA0 = (size_t)bx * 128;
  const size_t rowB0 = (size_t)by * 128;
  const int sgrp = wid * 2;
  const int r0 = (sgrp * 64 + lane) >> 2;
  const int r1 = ((sgrp + 1) * 64 + lane) >> 2;
  const int cc = ((lane & 3) ^ ((lane >> 3) & 3)) * 8;
  const int lr = lane & 15;
  const int koff = (((lane >> 4) ^ ((lr >> 1) & 3))) * 8;

  for (int k0 = 0; k0 < K; k0 += 32) {
    __syncthreads();
    __builtin_amdgcn_global_load_lds(
        (const AS1 void*)(A + (rowA0 + r0) * K + k0 + cc),
        (AS3 void*)(As + sgrp * 512), 16, 0, 0);
    __builtin_amdgcn_global_load_lds(
        (const AS1 void*)(A + (rowA0 + r1) * K + k0 + cc),
        (AS3 void*)(As + (sgrp + 1) * 512), 16, 0, 0);
    __builtin_amdgcn_global_load_lds(
        (const AS1 void*)(B + (rowB0 + r0) * K + k0 + cc),
        (AS3 void*)(Bs + sgrp * 512), 16, 0, 0);
    __builtin_amdgcn_global_load_lds(
        (const AS1 void*)(B + (rowB0 + r1) * K + k0 + cc),
        (AS3 void*)(Bs + (sgrp + 1) * 512), 16, 0, 0);
    __syncthreads();
    bf16x8 af[4], bf[4];
    #pragma unroll
    for (int m = 0; m < 4; ++m)
      af[m] = *reinterpret_cast<const bf16x8*>(&As[(wm + m * 16 + lr) * 32 + koff]);
    #pragma unroll
    for (int n = 0; n < 4; ++n)
      bf[n] = *reinterpret_cast<const bf16x8*>(&Bs[(wn + n * 16 + lr) * 32 + koff]);
    #pragma unroll
    for (int m = 0; m < 4; ++m)
      #pragma unroll
      for (int n = 0; n < 4; ++n)
        acc[m][n] = __builtin_amdgcn_mfma_f32_16x16x32_bf16(af[m], bf[n], acc[m][n], 0, 0, 0);
  }

  const int rg = (lane >> 4) * 4;
  #pragma unroll
  for (int m = 0; m < 4; ++m) {
    #pragma unroll
    for (int n = 0; n < 4; ++n) {
      #pragma unroll
      for (int r = 0; r < 4; ++r) {
        int row = (int)rowA0 + wm + m * 16 + rg + r;
        int col = (int)rowB0 + wn + n * 16 + lr;
        float v = acc[m][n][r];
        if (BIAS == 2) v += bias[row];
        C[(size_t)row * ldc + col] = f2bf(v);
      }
    }
  }
}

template<int BIAS>
__global__ __launch_bounds__(256, 2) void gemm_nt(
    const unsigned short* __restrict__ A, long sA,
    const unsigned short* __restrict__ B, long sB,
    unsigned short* __restrict__ Cp, long sC,
    int K, int ldc, const float* __restrict__ bias) {
  __shared__ unsigned short As[4096], Bs[4096];
  const int z = blockIdx.z;
  gemm128_body<BIAS>(As, Bs, A + (size_t)z * sA, B + (size_t)z * sB,
                     Cp + (size_t)z * sC, K, ldc, bias, blockIdx.x, blockIdx.y);
}

// Z (flat 0..511) and PVt (flat 512..1023) merged into one dispatch.
__global__ __launch_bounds__(256, 2) void gemm_dual(
    const unsigned short* __restrict__ Xt, const unsigned short* __restrict__ Mm,
    unsigned short* __restrict__ Z, const unsigned short* __restrict__ Wpv,
    unsigned short* __restrict__ PVt, const float* __restrict__ bvp) {
  __shared__ unsigned short As[4096], Bs[4096];
  const long NCe = (long)N_DIM * C_DIM;
  const long PVe = (long)C_DIM * N_DIM;
  int f = blockIdx.x;
  if (f < 512) {
    const int z = f >> 7, r = f & 127;  // 32 x 4 tiles: Z[j,a] = Xt . Mm^T
    gemm128_body<0>(As, Bs, Xt + (size_t)z * NCe, Mm, Z + (size_t)z * NCe,
                    C_DIM, C_DIM, nullptr, r & 31, r >> 5);
  } else {
    f -= 512;
    const int z = f >> 7, r = f & 127;  // 4 x 32 tiles: PVt[o,j] = Wpv . Xt^T + bvp
    gemm128_body<2>(As, Bs, Wpv, Xt + (size_t)z * NCe, PVt + (size_t)z * PVe,
                    C_DIM, N_DIM, bvp, r & 3, r >> 2);
  }
}

// ---------------- pipelined NT GEMM: 16 waves, BK=32, 2-parity prefetch -----
// Tile MROWS x 256, BK=32. 1024 thr = 16 waves (4m x 4n); per-wave out
// (MROWS/4) x 64, acc[MFR][4], MFR = MROWS/64. LDS = 2*(MROWS+256)*32*2B
// (<= 64 KB). ~110 VGPR -> 16 waves/CU (4/SIMD) vs old 8: cross-wave
// LDS-read/MFMA overlap between barriers.
// Per K-tile: BODY (ds_reads + MFMA, parity P; data staged 2 tiles ago);
// BAR; STAGE(P, k+2); vmcnt(2) [tile k+1 landed, k+2 in flight]; BAR.
// Sound: a wave reaches s_barrier only after its lgkmcnt-guarded MFMAs, so
// all parity-P reads complete before the k+2 DMA can overwrite parity P.
// Swizzle (proven conflict-free, gemm_nt pattern): 16B slot p of row r holds
// global slot p ^ ((r>>1)&3); staged via pre-swizzled global source (linear
// gload_lds dest), read with slot (lane>>4) ^ ((lr>>1)&3).
// MODE 0: store bf16 exp(scale*acc + bias[z*sBias + col])   (E with T-col).
// MODE 1: store f32 acc/colsum(B) + bias[row] + resid       (final output).
#define BAR() do { asm volatile("" ::: "memory"); __builtin_amdgcn_s_barrier(); \
                   asm volatile("" ::: "memory"); } while (0)

template<int MROWS, int MODE, int GX, int GY>
__global__ __launch_bounds__(1024, 4) void gemm_p(
    const unsigned short* __restrict__ A, long sA,
    const unsigned short* __restrict__ B, long sB,
    void* __restrict__ Cp, long sC,
    int K, int lda, int ldb, int ldc, float scale,
    const float* __restrict__ bias, long sBias,
    const float* __restrict__ resid, long sR) {
  constexpr int MFR  = MROWS / 64;      // m-frags per wave
  constexpr int ABUF = MROWS * 32;      // shorts per A parity buffer
  constexpr int BBUF = 256 * 32;
  __shared__ unsigned short lds[2 * ABUF + 2 * BBUF];
  unsigned short* Ab = lds;
  unsigned short* Bb = lds + 2 * ABUF;

  // XCD-aware bijective block swizzle (nwg % 8 == 0 at all call sites)
  int flat = blockIdx.x + GX * (blockIdx.y + GY * blockIdx.z);
  const int nwg = GX * GY * gridDim.z;
  flat = (flat & 7) * (nwg >> 3) + (flat >> 3);
  const int bx = flat & (GX - 1);
  const int by = (flat / GX) & (GY - 1);
  const int z  = flat / (GX * GY);

  const unsigned short* Ag = A + (size_t)z * sA + (size_t)bx * MROWS * lda;
  const unsigned short* Bg = B + (size_t)z * sB + (size_t)by * 256 * ldb;
  const int tid = threadIdx.x;
  const int wid = tid >> 6, lane = tid & 63;
  const int wrr = wid >> 2, wcc = wid & 3;
  const int lr = lane & 15, q = lane >> 4;

  // staging: thread u covers row u>>2, phys slot u&3, carries global slot
  // (u&3)^((u>>3)&3). For MROWS=128, waves 8-15 duplicate waves 0-7's A
  // (same source, same dest -> benign) to keep vmcnt uniform.
  const int uA = (MROWS == 256) ? tid : (tid & 511);
  const int agv = (uA >> 2) * lda + ((uA & 3) ^ ((uA >> 3) & 3)) * 8;
  const int bgv = (tid >> 2) * ldb + ((tid & 3) ^ ((tid >> 3) & 3)) * 8;
  const int wA = (MROWS == 256) ? wid : (wid & 7);

  auto STAGE = [&](int P, int tt) {  // P literal at call sites
    const int t32 = tt << 5;
    __builtin_amdgcn_global_load_lds(
        (const AS1 void*)(Ag + agv + t32),
        (AS3 void*)(Ab + P * ABUF + wA * 512), 16, 0, 0);
    __builtin_amdgcn_global_load_lds(
        (const AS1 void*)(Bg + bgv + t32),
        (AS3 void*)(Bb + P * BBUF + wid * 512), 16, 0, 0);
  };

  const int s0 = ((q ^ ((lr >> 1) & 3))) * 8;
  const unsigned short* aR = Ab + (wrr * (MROWS / 4) + lr) * 32 + s0;
  const unsigned short* bR = Bb + (wcc * 64 + lr) * 32 + s0;

  f32x4 acc[MFR][4] = {};
  f32x4 rsum[4] = {};
  bf16x8 onesf;
  #pragma unroll
  for (int i = 0; i < 8; ++i) onesf[i] = (__bf16)1.0f;

  auto BODY = [&](int P) {  // P literal at call sites
    bf16x8 af[MFR], bf[4];
    #pragma unroll
    for (int mi = 0; mi < MFR; ++mi)
      af[mi] = *reinterpret_cast<const bf16x8*>(aR + P * ABUF + mi * 512);
    #pragma unroll
    for (int n = 0; n < 4; ++n)
      bf[n] = *reinterpret_cast<const bf16x8*>(bR + P * BBUF + n * 512);
    __builtin_amdgcn_s_setprio(1);
    #pragma unroll
    for (int mi = 0; mi < MFR; ++mi)
      #pragma unroll
      for (int n = 0; n < 4; ++n)
        acc[mi][n] = __builtin_amdgcn_mfma_f32_16x16x32_bf16(af[mi], bf[n], acc[mi][n], 0, 0, 0);
    if (MODE == 1) {
      #pragma unroll
      for (int n = 0; n < 4; ++n)
        rsum[n] = __builtin_amdgcn_mfma_f32_16x16x32_bf16(onesf, bf[n], rsum[n], 0, 0, 0);
    }
    __builtin_amdgcn_s_setprio(0);
  };

  const int NT = K >> 5;  // even at all call sites
  STAGE(0, 0); STAGE(1, 1);
  asm volatile("s_waitcnt vmcnt(2)" ::: "memory");
  BAR();

  for (int k = 0; k < NT; k += 2) {
    BODY(0);
    BAR();
    if (k + 2 < NT) {
      STAGE(0, k + 2);
      asm volatile("s_waitcnt vmcnt(2)" ::: "memory");
    } else {
      asm volatile("s_waitcnt vmcnt(0)" ::: "memory");
    }
    BAR();
    BODY(1);
    if (k + 2 < NT) {
      BAR();
      if (k + 3 < NT) {
        STAGE(1, k + 3);
        asm volatile("s_waitcnt vmcnt(2)" ::: "memory");
      } else {
        asm volatile("s_waitcnt vmcnt(0)" ::: "memory");
      }
      BAR();
    }
  }

  const int rg = q * 4;
  if (MODE == 0) {
    unsigned short* Co = (unsigned short*)Cp + (size_t)z * sC;
    const float* Tz = bias + (size_t)z * sBias;
    #pragma unroll
    for (int m = 0; m < MFR; ++m)
      #pragma unroll
      for (int n = 0; n < 4; ++n) {
        const int col = by * 256 + wcc * 64 + n * 16 + lr;
        const float tb = Tz[col];
        #pragma unroll
        for (int r = 0; r < 4; ++r) {
          int row = bx * MROWS + wrr * (MROWS / 4) + m * 16 + rg + r;
          Co[(size_t)row * ldc + col] = f2bf(__expf(acc[m][n][r] * scale + tb));
        }
      }
  } else {
    float* Co = (float*)Cp + (size_t)z * sC;
    const float* Rs = resid + (size_t)z * sR;
    #pragma unroll
    for (int m = 0; m < MFR; ++m)
      #pragma unroll
      for (int n = 0; n < 4; ++n)
        #pragma unroll
        for (int r = 0; r < 4; ++r) {
          int row = bx * MROWS + wrr * (MROWS / 4) + m * 16 + rg + r;
          int col = by * 256 + wcc * 64 + n * 16 + lr;
          size_t idx = (size_t)row * ldc + col;
          Co[idx] = acc[m][n][r] / rsum[n][r] + bias[row] + Rs[idx];
        }
  }
}

extern "C" void kernel_launch(void* const* d_in, const int* in_sizes, int n_in,
                              void* d_out, int out_size, void* d_ws, size_t ws_size,
                              hipStream_t stream) {
  const float* x  = (const float*)d_in[0];
  const float* wq = (const float*)d_in[1];
  const float* bq = (const float*)d_in[2];
  const float* wk = (const float*)d_in[3];
  const float* bv = (const float*)d_in[6];
  const float* wv = (const float*)d_in[5];
  const float* wp = (const float*)d_in[7];
  const float* bp = (const float*)d_in[8];
  float* out = (float*)d_out;
  char* ws = (char*)d_ws;
  const size_t MB = 1024 * 1024;
  const long W2 = (long)C_DIM * C_DIM;
  unsigned short* Wqt = (unsigned short*)(ws + 0);                // [c,o] bf16
  unsigned short* Wpb = (unsigned short*)(ws + 512 * 1024);       // [o,c] bf16
  unsigned short* Wkt = (unsigned short*)(ws + 1 * MB);           // [c,o]
  unsigned short* Wvt = (unsigned short*)(ws + MB + 512 * 1024);  // [c,o]
  unsigned short* Mm  = (unsigned short*)(ws + 2 * MB);           // M = Wq^T Wk
  unsigned short* Wpv = (unsigned short*)(ws + 2 * MB + 512 * 1024);
  float* u   = (float*)(ws + 3 * MB);            // Wk^T bq [512]
  float* bvp = (float*)(ws + 3 * MB + 8 * 1024); // Wp bv   [512]
  float* Tf  = (float*)(ws + 4 * MB);            // T [B*N] f32
  unsigned short* Xt  = (unsigned short*)(ws + 5 * MB);   // [B,N,C]
  unsigned short* Z   = (unsigned short*)(ws + 21 * MB);  // [B,N,C]  Xt.M^T
  unsigned short* PVt = (unsigned short*)(ws + 37 * MB);  // [B,C,N]  Wpv.Xt^T
  unsigned short* P   = (unsigned short*)(ws + 53 * MB);  // E [N,N] x (1|4)
  const long NCe = (long)N_DIM * C_DIM;
  const long NNe = (long)N_DIM * N_DIM;
  const long PVe = (long)C_DIM * N_DIM;
  const float rs = 0.044194173824159216f;  // 1/sqrt(512)
  const bool big = ws_size >= 53 * MB + 4 * (size_t)N_DIM * N_DIM * 2;

  cvtT_weights<<<dim3(16, 16, 4), dim3(32, 8), 0, stream>>>(
      wq, wk, wv, wp, Wqt, Wkt, Wvt, Wpb);
  vec_prep<<<dim3(16), dim3(64), 0, stream>>>(wk, bq, wp, bv, u, bvp);
  // z=0: Mm = NT(Wqt, Wkt); z=1: Wpv = NT(Wpb, Wvt)
  gemm_nt<0><<<dim3(4, 4, 2), 256, 0, stream>>>(
      Wqt, W2, Wkt, W2, Mm, W2, C_DIM, C_DIM, nullptr);
  transpose_x<<<dim3(N_DIM / 32, C_DIM / 32, B_DIM), dim3(32, 8), 0, stream>>>(x, Xt);
  rowdot_T<<<dim3(B_DIM * N_DIM / 4), 256, 0, stream>>>(Xt, u, Tf);
  // merged: Z = Xt.Mm^T  and  PVt = Wpv.Xt^T + bvp
  gemm_dual<<<dim3(1024), 256, 0, stream>>>(Xt, Mm, Z, Wpv, PVt, bvp);

  if (big) {
    // E = exp(rs * Xt.Z^T + T[col])
    gemm_p<256, 0, 16, 16><<<dim3(16, 16, 4), 1024, 0, stream>>>(
        Xt, NCe, Z, NCe, P, NNe, C_DIM, C_DIM, C_DIM, N_DIM, rs,
        Tf, N_DIM, nullptr, 0);
    // out[o,n] = sum_j PVt[o,j] E[n,j] / colsum_j E[n,j] + bp[o] + x[o,n]
    gemm_p<128, 1, 4, 16><<<dim3(4, 16, 4), 1024, 0, stream>>>(
        PVt, PVe, P, NNe, out, NCe, N_DIM, N_DIM, N_DIM, N_DIM, 1.0f,
        bp, 0, x, NCe);
  } else {
    for (int b = 0; b < B_DIM; ++b) {
      gemm_p<256, 0, 16, 16><<<dim3(16, 16, 1), 1024, 0, stream>>>(
          Xt + (size_t)b * NCe, 0, Z + (size_t)b * NCe, 0, P, 0,
          C_DIM, C_DIM, C_DIM, N_DIM, rs, Tf + (size_t)b * N_DIM, 0, nullptr, 0);
      gemm_p<128, 1, 4, 16><<<dim3(4, 16, 1), 1024, 0, stream>>>(
          PVt + (size_t)b * PVe, 0, P, 0, (void*)(out + (size_t)b * NCe), 0,
          N_DIM, N_DIM, N_DIM, N_DIM, 1.0f, bp, 0, x + (size_t)b * NCe, 0);
    }
  }
}

// Round 10
// 244.546 us; speedup vs baseline: 1.1157x; 1.1157x over previous
//
#include <hip/hip_runtime.h>
#include <hip/hip_bf16.h>
#include <stdint.h>

// B=4, C=512, H=W=64 -> N=4096. Channel-first x [B,C,N].
#define C_DIM 512
#define N_DIM 4096
#define B_DIM 4

typedef __bf16 bf16x8 __attribute__((ext_vector_type(8)));
typedef float f32x4 __attribute__((ext_vector_type(4)));
#define AS1 __attribute__((address_space(1)))
#define AS3 __attribute__((address_space(3)))

static __device__ __forceinline__ unsigned short f2bf(float x) {
  unsigned u = __float_as_uint(x);
  unsigned r = (u + 0x7fffu + ((u >> 16) & 1u)) >> 16;
  return (unsigned short)r;
}

__global__ __launch_bounds__(256) void cvt_weights(
    const float* __restrict__ w0, const float* __restrict__ w1,
    const float* __restrict__ w2, const float* __restrict__ w3,
    unsigned short* __restrict__ o0, unsigned short* __restrict__ o1,
    unsigned short* __restrict__ o2, unsigned short* __restrict__ o3) {
  int i = blockIdx.x * blockDim.x + threadIdx.x;
  if (i < C_DIM * C_DIM) {
    o0[i] = f2bf(w0[i]); o1[i] = f2bf(w1[i]);
    o2[i] = f2bf(w2[i]); o3[i] = f2bf(w3[i]);
  }
}

// x [B,C,N] f32 -> Xt [B,N,C] bf16
__global__ __launch_bounds__(256) void transpose_x(
    const float* __restrict__ x, unsigned short* __restrict__ Xt) {
  __shared__ float t[32][33];
  const int b = blockIdx.z;
  const float* xb = x + (size_t)b * C_DIM * N_DIM;
  unsigned short* xtb = Xt + (size_t)b * N_DIM * C_DIM;
  const int n0 = blockIdx.x * 32, c0 = blockIdx.y * 32;
  const int tx = threadIdx.x, ty = threadIdx.y;
  #pragma unroll
  for (int i = ty; i < 32; i += 8)
    t[i][tx] = xb[(size_t)(c0 + i) * N_DIM + n0 + tx];
  __syncthreads();
  #pragma unroll
  for (int i = ty; i < 32; i += 8)
    xtb[(size_t)(n0 + i) * C_DIM + c0 + tx] = f2bf(t[tx][i]);
}

__global__ __launch_bounds__(256) void zero_buf(float* __restrict__ p, int n) {
  int i = blockIdx.x * 256 + threadIdx.x;
  if (i < n) p[i] = 0.f;
}

// ---------------- 128^2-tile 2-phase NT GEMM body --------------------------
// C[i,j] = sum_k A[i,k]B[j,k]; BIAS: 0 none, 1 +bias[col]. bf16 out.
template<int BIAS>
__device__ __forceinline__ void gemm128_body(
    unsigned short* As, unsigned short* Bs,
    const unsigned short* __restrict__ A, const unsigned short* __restrict__ B,
    unsigned short* __restrict__ C, int K, int ldc,
    const float* __restrict__ bias, int bx, int by) {
  const int tid = threadIdx.x;
  const int wid = tid >> 6, lane = tid & 63;
  const int wm = (wid >> 1) * 64, wn = (wid & 1) * 64;
  f32x4 acc[4][4] = {};
  const size_t rowA0 = (size_t)bx * 128;
  const size_t rowB0 = (size_t)by * 128;
  const int sgrp = wid * 2;
  const int r0 = (sgrp * 64 + lane) >> 2;
  const int r1 = ((sgrp + 1) * 64 + lane) >> 2;
  const int cc = ((lane & 3) ^ ((lane >> 3) & 3)) * 8;
  const int lr = lane & 15;
  const int koff = (((lane >> 4) ^ ((lr >> 1) & 3))) * 8;

  for (int k0 = 0; k0 < K; k0 += 32) {
    __syncthreads();
    __builtin_amdgcn_global_load_lds(
        (const AS1 void*)(A + (rowA0 + r0) * K + k0 + cc),
        (AS3 void*)(As + sgrp * 512), 16, 0, 0);
    __builtin_amdgcn_global_load_lds(
        (const AS1 void*)(A + (rowA0 + r1) * K + k0 + cc),
        (AS3 void*)(As + (sgrp + 1) * 512), 16, 0, 0);
    __builtin_amdgcn_global_load_lds(
        (const AS1 void*)(B + (rowB0 + r0) * K + k0 + cc),
        (AS3 void*)(Bs + sgrp * 512), 16, 0, 0);
    __builtin_amdgcn_global_load_lds(
        (const AS1 void*)(B + (rowB0 + r1) * K + k0 + cc),
        (AS3 void*)(Bs + (sgrp + 1) * 512), 16, 0, 0);
    __syncthreads();
    bf16x8 af[4], bf[4];
    #pragma unroll
    for (int m = 0; m < 4; ++m)
      af[m] = *reinterpret_cast<const bf16x8*>(&As[(wm + m * 16 + lr) * 32 + koff]);
    #pragma unroll
    for (int n = 0; n < 4; ++n)
      bf[n] = *reinterpret_cast<const bf16x8*>(&Bs[(wn + n * 16 + lr) * 32 + koff]);
    #pragma unroll
    for (int m = 0; m < 4; ++m)
      #pragma unroll
      for (int n = 0; n < 4; ++n)
        acc[m][n] = __builtin_amdgcn_mfma_f32_16x16x32_bf16(af[m], bf[n], acc[m][n], 0, 0, 0);
  }

  const int rg = (lane >> 4) * 4;
  #pragma unroll
  for (int m = 0; m < 4; ++m) {
    #pragma unroll
    for (int n = 0; n < 4; ++n) {
      const int col = (int)rowB0 + wn + n * 16 + lr;
      #pragma unroll
      for (int r = 0; r < 4; ++r) {
        int row = (int)rowA0 + wm + m * 16 + rg + r;
        float v = acc[m][n][r];
        if (BIAS == 1) v += bias[col];
        C[(size_t)row * ldc + col] = f2bf(v);
      }
    }
  }
}

// merged Q,K,V projections: grid (32, 4, 12); z = wsel + 3*batch
__global__ __launch_bounds__(256, 2) void gemm_qkv(
    const unsigned short* __restrict__ Xt,
    const unsigned short* __restrict__ Wq, const unsigned short* __restrict__ Wk,
    const unsigned short* __restrict__ Wv,
    const float* __restrict__ bq, const float* __restrict__ bk,
    const float* __restrict__ bv,
    unsigned short* __restrict__ Qb, unsigned short* __restrict__ Kb,
    unsigned short* __restrict__ Vb) {
  __shared__ unsigned short As[4096], Bs[4096];
  const long NCe = (long)N_DIM * C_DIM;
  const int z = blockIdx.z;
  const int wsel = z % 3, bat = z / 3;
  const unsigned short* W = wsel == 0 ? Wq : wsel == 1 ? Wk : Wv;
  const float* bias = wsel == 0 ? bq : wsel == 1 ? bk : bv;
  unsigned short* O = (wsel == 0 ? Qb : wsel == 1 ? Kb : Vb) + (size_t)bat * NCe;
  gemm128_body<1>(As, Bs, Xt + (size_t)bat * NCe, W, O, C_DIM, C_DIM, bias,
                  blockIdx.x, blockIdx.y);
}

// PVt[o,j] = sum_c Wp[o,c] V[j,c]; grid (4, 32, 4)
__global__ __launch_bounds__(256, 2) void gemm_pvt(
    const unsigned short* __restrict__ Wp, const unsigned short* __restrict__ Vb,
    unsigned short* __restrict__ PVt) {
  __shared__ unsigned short As[4096], Bs[4096];
  const long NCe = (long)N_DIM * C_DIM;
  const long PVe = (long)C_DIM * N_DIM;
  const int z = blockIdx.z;
  gemm128_body<0>(As, Bs, Wp, Vb + (size_t)z * NCe, PVt + (size_t)z * PVe,
                  C_DIM, N_DIM, nullptr, blockIdx.x, blockIdx.y);
}

// ---------------- pipelined NT GEMM (R8 structure, best measured) -----------
// A-tile MT=MF*32 x BK=64; B-tile 256 x 64. 8 waves (2M x 4N), acc[MF][4].
// K-loop unrolled by 2 (compile-time parity); ds_reads = lane-constant ptr +
// imm; staging = SGPR base + per-lane voffset + tt*64. Per tile: BODY; BAR;
// STAGE(P,k+2); vmcnt(LOADS); BAR  (race-free per R6 analysis).
// Swizzle: 16B slot p of row r holds global slot p ^ (r&7) (both sides).
// MODE 0: store bf16 exp(scale*acc); row-sums of exp -> atomicAdd denom[row].
// MODE 1: store f32 acc/denom[col] + bias[row] + resid  (final output).
#define BAR() do { asm volatile("" ::: "memory"); __builtin_amdgcn_s_barrier(); \
                   asm volatile("" ::: "memory"); } while (0)

template<int MF, int MODE, int GX, int GY>
__global__ __launch_bounds__(512, 2) void gemm_p(
    const unsigned short* __restrict__ A, long sA,
    const unsigned short* __restrict__ B, long sB,
    void* __restrict__ Cp, long sC,
    int K, int lda, int ldb, int ldc, float scale,
    const float* __restrict__ bias,
    float* __restrict__ denom, long sDen,
    const float* __restrict__ resid, long sR) {
  constexpr int MT     = MF * 32;
  constexpr int ABUF   = MT * 64;
  constexpr int MB2    = MF / 2;
  constexpr int ALOADS = (MT / 128) * 2;
  constexpr int LOADS  = ALOADS + 4;
  __shared__ unsigned short lds[2 * ABUF + 32768];
  unsigned short* Ab = lds;
  unsigned short* Bb = lds + 2 * ABUF;

  // XCD-aware bijective block swizzle (nwg % 8 == 0 at all call sites)
  int flat = blockIdx.x + GX * (blockIdx.y + GY * blockIdx.z);
  const int nwg = GX * GY * gridDim.z;
  flat = (flat & 7) * (nwg >> 3) + (flat >> 3);
  const int bx = flat & (GX - 1);
  const int by = (flat / GX) & (GY - 1);
  const int z  = flat / (GX * GY);

  const unsigned short* Ag = A + (size_t)z * sA + (size_t)bx * MT * lda;
  const unsigned short* Bg = B + (size_t)z * sB + (size_t)by * 256 * ldb;
  const int tid = threadIdx.x;
  const int wid = tid >> 6, lane = tid & 63;
  const int wr = wid >> 2, wc = wid & 3;
  const int lr = lane & 15, q = lane >> 4;
  const int ssl = (lane & 7) ^ ((lane >> 3) & 7);
  const int sw = lr & 7;
  const int s0 = (q ^ sw) * 8;
  const int s1 = s0 ^ 32;

  const unsigned short* a0 = Ab + (wr * (MT / 2) + lr) * 64 + s0;
  const unsigned short* a1 = Ab + (wr * (MT / 2) + lr) * 64 + s1;
  const unsigned short* b0 = Bb + (wc * 64 + lr) * 64 + s0;
  const unsigned short* b1 = Bb + (wc * 64 + lr) * 64 + s1;

  int agv[ALOADS], bgv[4];
  #pragma unroll
  for (int i = 0; i < ALOADS; ++i)
    agv[i] = ((i >> 1) * 128 + (wid * 2 + (i & 1)) * 8 + (lane >> 3)) * lda + ssl * 8;
  #pragma unroll
  for (int i = 0; i < 4; ++i)
    bgv[i] = ((i >> 1) * 128 + (wid * 2 + (i & 1)) * 8 + (lane >> 3)) * ldb + ssl * 8;

  auto STAGE = [&](int P, int tt) {
    const int t64 = tt << 6;
    #pragma unroll
    for (int i = 0; i < ALOADS; ++i)
      __builtin_amdgcn_global_load_lds(
          (const AS1 void*)(Ag + agv[i] + t64),
          (AS3 void*)(Ab + P * ABUF + (i >> 1) * 8192 + (wid * 2 + (i & 1)) * 512),
          16, 0, 0);
    #pragma unroll
    for (int i = 0; i < 4; ++i)
      __builtin_amdgcn_global_load_lds(
          (const AS1 void*)(Bg + bgv[i] + t64),
          (AS3 void*)(Bb + P * 16384 + (i >> 1) * 8192 + (wid * 2 + (i & 1)) * 512),
          16, 0, 0);
  };

  f32x4 acc[MF][4] = {};

  auto BODY = [&](int P) {
    const int ao = P * ABUF;
    const int bo = P * 16384;
    bf16x8 af[MB2][2], ah[MB2][2], bA[2][2], bB[2][2];
    #pragma unroll
    for (int mi = 0; mi < MB2; ++mi) {
      af[mi][0] = *reinterpret_cast<const bf16x8*>(a0 + ao + mi * 1024);
      af[mi][1] = *reinterpret_cast<const bf16x8*>(a1 + ao + mi * 1024);
    }
    #pragma unroll
    for (int n = 0; n < 2; ++n) {
      bA[n][0] = *reinterpret_cast<const bf16x8*>(b0 + bo + n * 1024);
      bA[n][1] = *reinterpret_cast<const bf16x8*>(b1 + bo + n * 1024);
      bB[n][0] = *reinterpret_cast<const bf16x8*>(b0 + bo + (2 + n) * 1024);
      bB[n][1] = *reinterpret_cast<const bf16x8*>(b1 + bo + (2 + n) * 1024);
    }
    #pragma unroll
    for (int mi = 0; mi < MB2; ++mi) {
      ah[mi][0] = *reinterpret_cast<const bf16x8*>(a0 + ao + (MB2 + mi) * 1024);
      ah[mi][1] = *reinterpret_cast<const bf16x8*>(a1 + ao + (MB2 + mi) * 1024);
    }
    #pragma unroll
    for (int kk = 0; kk < 2; ++kk)
      #pragma unroll
      for (int mi = 0; mi < MB2; ++mi)
        #pragma unroll
        for (int n = 0; n < 2; ++n) {
          acc[mi][n]     = __builtin_amdgcn_mfma_f32_16x16x32_bf16(af[mi][kk], bA[n][kk], acc[mi][n], 0, 0, 0);
          acc[mi][2 + n] = __builtin_amdgcn_mfma_f32_16x16x32_bf16(af[mi][kk], bB[n][kk], acc[mi][2 + n], 0, 0, 0);
        }
    #pragma unroll
    for (int kk = 0; kk < 2; ++kk)
      #pragma unroll
      for (int mi = 0; mi < MB2; ++mi)
        #pragma unroll
        for (int n = 0; n < 2; ++n) {
          acc[MB2 + mi][n]     = __builtin_amdgcn_mfma_f32_16x16x32_bf16(ah[mi][kk], bA[n][kk], acc[MB2 + mi][n], 0, 0, 0);
          acc[MB2 + mi][2 + n] = __builtin_amdgcn_mfma_f32_16x16x32_bf16(ah[mi][kk], bB[n][kk], acc[MB2 + mi][2 + n], 0, 0, 0);
        }
  };

  auto WAITV = [&]() {
    if (LOADS == 8) asm volatile("s_waitcnt vmcnt(8)" ::: "memory");
    else            asm volatile("s_waitcnt vmcnt(6)" ::: "memory");
  };

  const int NT = K >> 6;
  STAGE(0, 0); STAGE(1, 1);
  WAITV();
  BAR();

  for (int k = 0; k < NT; k += 2) {
    BODY(0);
    BAR();
    if (k + 2 < NT) { STAGE(0, k + 2); WAITV(); }
    else { asm volatile("s_waitcnt vmcnt(0)" ::: "memory"); }
    BAR();
    BODY(1);
    if (k + 2 < NT) {
      BAR();
      if (k + 3 < NT) { STAGE(1, k + 3); WAITV(); }
      else { asm volatile("s_waitcnt vmcnt(0)" ::: "memory"); }
      BAR();
    }
  }

  const int rg = q * 4;
  if (MODE == 0) {
    unsigned short* Co = (unsigned short*)Cp + (size_t)z * sC;
    float* Dz = denom + (size_t)z * sDen;
    #pragma unroll
    for (int m = 0; m < MF; ++m) {
      float ev[4][4];
      #pragma unroll
      for (int n = 0; n < 4; ++n) {
        const int col = by * 256 + wc * 64 + n * 16 + lr;
        #pragma unroll
        for (int r = 0; r < 4; ++r) {
          int row = bx * MT + wr * (MT / 2) + m * 16 + rg + r;
          ev[n][r] = __expf(acc[m][n][r] * scale);
          Co[(size_t)row * ldc + col] = f2bf(ev[n][r]);
        }
      }
      // partial row-sum over this wave's 64 cols -> atomic per row
      #pragma unroll
      for (int r = 0; r < 4; ++r) {
        float s = (ev[0][r] + ev[1][r]) + (ev[2][r] + ev[3][r]);
        s += __shfl_xor(s, 1); s += __shfl_xor(s, 2);
        s += __shfl_xor(s, 4); s += __shfl_xor(s, 8);
        if (lr == 0) {
          int row = bx * MT + wr * (MT / 2) + m * 16 + rg + r;
          atomicAdd(&Dz[row], s);
        }
      }
    }
  } else {
    float* Co = (float*)Cp + (size_t)z * sC;
    const float* Rs = resid + (size_t)z * sR;
    const float* Dz = denom + (size_t)z * sDen;
    #pragma unroll
    for (int n = 0; n < 4; ++n) {
      const int col = by * 256 + wc * 64 + n * 16 + lr;
      const float dinv = 1.0f / Dz[col];
      #pragma unroll
      for (int m = 0; m < MF; ++m)
        #pragma unroll
        for (int r = 0; r < 4; ++r) {
          int row = bx * MT + wr * (MT / 2) + m * 16 + rg + r;
          size_t idx = (size_t)row * ldc + col;
          Co[idx] = acc[m][n][r] * dinv + bias[row] + Rs[idx];
        }
    }
  }
}

extern "C" void kernel_launch(void* const* d_in, const int* in_sizes, int n_in,
                              void* d_out, int out_size, void* d_ws, size_t ws_size,
                              hipStream_t stream) {
  const float* x  = (const float*)d_in[0];
  const float* wq = (const float*)d_in[1];
  const float* bq = (const float*)d_in[2];
  const float* wk = (const float*)d_in[3];
  const float* bk = (const float*)d_in[4];
  const float* wv = (const float*)d_in[5];
  const float* bv = (const float*)d_in[6];
  const float* wp = (const float*)d_in[7];
  const float* bp = (const float*)d_in[8];
  float* out = (float*)d_out;
  char* ws = (char*)d_ws;
  const size_t MB = 1024 * 1024;
  unsigned short* Wq  = (unsigned short*)(ws + 0);
  unsigned short* Wk  = (unsigned short*)(ws + 512 * 1024);
  unsigned short* Wv  = (unsigned short*)(ws + 1 * MB);
  unsigned short* Wp  = (unsigned short*)(ws + MB + 512 * 1024);
  unsigned short* Xt  = (unsigned short*)(ws + 2 * MB);    // [B,N,C] bf16
  unsigned short* Qb  = (unsigned short*)(ws + 18 * MB);   // [B,N,C]
  unsigned short* Kb  = (unsigned short*)(ws + 34 * MB);   // [B,N,C]
  unsigned short* Vb  = (unsigned short*)(ws + 50 * MB);   // [B,N,C] (dead after PVt)
  unsigned short* PVt = (unsigned short*)(ws + 66 * MB);   // [B,C,N]
  unsigned short* P   = (unsigned short*)(ws + 82 * MB);   // E [N,N] x (1|4)
  float* denom = (float*)(ws + 50 * MB);  // overlays dead Vb after PVt
  const long NCe = (long)N_DIM * C_DIM;
  const long NNe = (long)N_DIM * N_DIM;
  const long PVe = (long)C_DIM * N_DIM;
  const float rs = 0.044194173824159216f;  // 1/sqrt(512)
  const bool big = ws_size >= 82 * MB + 4 * (size_t)N_DIM * N_DIM * 2;

  cvt_weights<<<dim3((C_DIM * C_DIM + 255) / 256), 256, 0, stream>>>(
      wq, wk, wv, wp, Wq, Wk, Wv, Wp);
  transpose_x<<<dim3(N_DIM / 32, C_DIM / 32, B_DIM), dim3(32, 8), 0, stream>>>(x, Xt);
  // Q,K,V in one dispatch (1536 blocks)
  gemm_qkv<<<dim3(32, 4, 12), 256, 0, stream>>>(
      Xt, Wq, Wk, Wv, bq, bk, bv, Qb, Kb, Vb);
  // PVt = Wp . V^T  (folds output projection into PV)
  gemm_pvt<<<dim3(4, 32, 4), 256, 0, stream>>>(Wp, Vb, PVt);

  if (big) {
    zero_buf<<<dim3(B_DIM * N_DIM / 256), 256, 0, stream>>>(denom, B_DIM * N_DIM);
    // E = exp(rs * Q.K^T); denom[n] += rowsum
    gemm_p<8, 0, 16, 16><<<dim3(16, 16, 4), 512, 0, stream>>>(
        Qb, NCe, Kb, NCe, P, NNe, C_DIM, C_DIM, C_DIM, N_DIM, rs,
        nullptr, denom, N_DIM, nullptr, 0);
    // out[o,n] = (sum_j PVt[o,j] E[n,j]) / denom[n] + bp[o] + x[o,n]
    gemm_p<4, 1, 4, 16><<<dim3(4, 16, 4), 512, 0, stream>>>(
        PVt, PVe, P, NNe, out, NCe, N_DIM, N_DIM, N_DIM, N_DIM, 1.0f,
        bp, denom, N_DIM, x, NCe);
  } else {
    for (int b = 0; b < B_DIM; ++b) {
      zero_buf<<<dim3(N_DIM / 256), 256, 0, stream>>>(denom, N_DIM);
      gemm_p<8, 0, 16, 16><<<dim3(16, 16, 1), 512, 0, stream>>>(
          Qb + (size_t)b * NCe, 0, Kb + (size_t)b * NCe, 0, P, 0,
          C_DIM, C_DIM, C_DIM, N_DIM, rs, nullptr, denom, 0, nullptr, 0);
      gemm_p<4, 1, 4, 16><<<dim3(4, 16, 1), 512, 0, stream>>>(
          PVt + (size_t)b * PVe, 0, P, 0, (void*)(out + (size_t)b * NCe), 0,
          N_DIM, N_DIM, N_DIM, N_DIM, 1.0f, bp, denom, 0, x + (size_t)b * NCe, 0);
    }
  }
}